// Round 8
// baseline (208.893 us; speedup 1.0000x reference)
//
#include <hip/hip_runtime.h>
#include <hip/hip_bf16.h>

// Problem constants (B=2, S=2048, D=1024, H=16, dk=64)
#define B_   2
#define S_   2048
#define H_   16
#define DK_  64
#define D_   1024
#define BS_  4096   // B*S
#define N3_  3072   // 3*D

typedef __attribute__((ext_vector_type(8))) short short8;    // 8 x bf16 (4 VGPRs)
typedef __attribute__((ext_vector_type(4))) float floatx4;   // 16x16 MFMA acc
typedef __attribute__((ext_vector_type(16))) float floatx16; // 32x32 MFMA acc
typedef __hip_bfloat16 bf16;

__device__ inline void load_lds16(const bf16* g, bf16* l) {
    __builtin_amdgcn_global_load_lds(
        (const __attribute__((address_space(1))) void*)g,
        (__attribute__((address_space(3))) void*)l, 16, 0, 0);
}

__device__ inline unsigned int pack2bf16(float a, float b) {
    __hip_bfloat162 h = __float22bfloat162_rn(make_float2(a, b));
    return *(unsigned int*)&h;
}

// ---------------- fused fp32 -> bf16 convert for all inputs (1 launch) ----------------
__global__ void cvt_all(const float* __restrict__ x,  const float* __restrict__ wq,
                        const float* __restrict__ wk, const float* __restrict__ wv,
                        const float* __restrict__ wo,
                        bf16* __restrict__ xb, bf16* __restrict__ wcat, bf16* __restrict__ wob) {
    const int blk = blockIdx.x;
    const float* src; bf16* dst; int base;
    if (blk < 4096)      { src = x;  dst = xb;             base = blk * 1024; }
    else if (blk < 5120) { src = wq; dst = wcat;           base = (blk - 4096) * 1024; }
    else if (blk < 6144) { src = wk; dst = wcat + 1048576; base = (blk - 5120) * 1024; }
    else if (blk < 7168) { src = wv; dst = wcat + 2097152; base = (blk - 6144) * 1024; }
    else                 { src = wo; dst = wob;            base = (blk - 7168) * 1024; }
    const int i = base + threadIdx.x * 4;
    float4 v = *(const float4*)(src + i);
    *(uint2*)(dst + i) = make_uint2(pack2bf16(v.x, v.y), pack2bf16(v.z, v.w));
}

// ---------------- QKV GEMM (BK=64, swizzled LDS): Q,K -> QKVb rows; V -> Vt ----------------
__global__ __launch_bounds__(256)
void gemm_qkv(const bf16* __restrict__ A, const bf16* __restrict__ Bw,
              bf16* __restrict__ Cqk, bf16* __restrict__ Vt) {
    __shared__ __align__(16) bf16 lA[128 * 64];   // 16 KB
    __shared__ __align__(16) bf16 lB[128 * 64];   // 16 KB
    const int t = threadIdx.x;
    const int lane = t & 63, w = t >> 6;
    const int quad = lane >> 4, l16 = lane & 15;
    const int m0 = blockIdx.x * 128, n0 = blockIdx.y * 128;
    const int wm = (w & 1) * 64, wn = (w >> 1) * 64;

    floatx4 acc[4][4];
#pragma unroll
    for (int i = 0; i < 4; i++)
#pragma unroll
        for (int j = 0; j < 4; j++) acc[i][j] = (floatx4){0.f, 0.f, 0.f, 0.f};

    const int srow = t >> 3;                 // 0..31
    const int sj   = (t & 7) ^ (srow & 7);   // XOR-swizzled 16B chunk

    for (int kt = 0; kt < D_; kt += 64) {
#pragma unroll
        for (int r = 0; r < 4; r++)
            load_lds16(A + (size_t)(m0 + r * 32 + srow) * D_ + kt + sj * 8,
                       lA + r * 2048 + t * 8);
#pragma unroll
        for (int r = 0; r < 4; r++)
            load_lds16(Bw + (size_t)(n0 + r * 32 + srow) * D_ + kt + sj * 8,
                       lB + r * 2048 + t * 8);
        __syncthreads();

#pragma unroll
        for (int kh = 0; kh < 2; kh++) {
            short8 af[4], bfr[4];
#pragma unroll
            for (int i = 0; i < 4; i++) {
                const int row = wm + i * 16 + l16;
                af[i] = *(const short8*)&lA[row * 64 + ((kh * 4 + quad) ^ (row & 7)) * 8];
            }
#pragma unroll
            for (int j = 0; j < 4; j++) {
                const int row = wn + j * 16 + l16;
                bfr[j] = *(const short8*)&lB[row * 64 + ((kh * 4 + quad) ^ (row & 7)) * 8];
            }
#pragma unroll
            for (int i = 0; i < 4; i++)
#pragma unroll
                for (int j = 0; j < 4; j++)
                    acc[i][j] = __builtin_amdgcn_mfma_f32_16x16x32_bf16(af[i], bfr[j], acc[i][j], 0, 0, 0);
        }
        __syncthreads();
    }

    if (n0 < 2 * D_) {
        // Q,K columns: row-major coalesced store
#pragma unroll
        for (int i = 0; i < 4; i++) {
            const int row = m0 + wm + i * 16 + quad * 4;
#pragma unroll
            for (int j = 0; j < 4; j++) {
                const int col = n0 + wn + j * 16 + l16;
#pragma unroll
                for (int r = 0; r < 4; r++)
                    Cqk[(size_t)(row + r) * N3_ + col] = __float2bfloat16(acc[i][j][r]);
            }
        }
    } else {
        // V columns: transposed packed store into Vt (B,H,64,S)
#pragma unroll
        for (int i = 0; i < 4; i++) {
            const int row0 = m0 + wm + i * 16 + quad * 4;
            const int bb = row0 >> 11;
            const int ss = row0 & 2047;
#pragma unroll
            for (int j = 0; j < 4; j++) {
                const int c = n0 + wn + j * 16 + l16 - 2 * D_;
                const int h = c >> 6, d = c & 63;
                *(uint2*)(Vt + (((size_t)bb * H_ + h) * 64 + d) * S_ + ss) =
                    make_uint2(pack2bf16(acc[i][j][0], acc[i][j][1]),
                               pack2bf16(acc[i][j][2], acc[i][j][3]));
            }
        }
    }
}

// ---------------- RoPE: QKV (B,S,3D) -> Qr (scaled by log2e/sqrt(dk)), Kr (B,H,S,64) ----------------
__global__ void rope_kernel(const bf16* __restrict__ QKV,
                            bf16* __restrict__ Qr, bf16* __restrict__ Kr) {
    int tid = blockIdx.x * blockDim.x + threadIdx.x;
    if (tid >= B_ * S_ * H_ * 32) return;
    const int i = tid & 31;
    const int h = (tid >> 5) & (H_ - 1);
    const int bs = tid >> 9;
    const int s = bs & (S_ - 1);
    const int b = bs >> 11;

    const bf16* base = QKV + (size_t)bs * N3_ + h * 64 + 2 * i;
    const float q0 = __bfloat162float(base[0]);
    const float q1 = __bfloat162float(base[1]);
    const float k0 = __bfloat162float(base[D_]);
    const float k1 = __bfloat162float(base[D_ + 1]);

    const float freq = exp2f(-(float)(2 * i) * 0.2076205059304601f);  // theta^(-2i/64)
    const float ang = (float)s * freq;
    float sn, cs;
    sincosf(ang, &sn, &cs);

    const float QS = 0.18033688011112042f;   // log2(e)/sqrt(64)
    const size_t off = ((size_t)(b * H_ + h) * S_ + s) * 64 + 2 * i;
    *(unsigned int*)(Qr + off) = pack2bf16((q0 * cs - q1 * sn) * QS, (q0 * sn + q1 * cs) * QS);
    *(unsigned int*)(Kr + off) = pack2bf16(k0 * cs - k1 * sn, k0 * sn + k1 * cs);
}

// ---------------- Flash attention (causal), 32x32 MFMA, wave = 32 q rows ----------------
// 128-thread blocks (2 waves = 64 q-tile), grid (32, 32), qblk = 31 - blockIdx.x.
// S^T = K.Q^T via mfma_32x32x16: C-layout col = q = lane&31,
// row = key_local = (reg&3) + 8*(reg>>2) + 4*(lane>>5). Fixed-max base-2 softmax.
// PV: O^T = V^T.P^T, P routed through per-wave LDS chunk (32 keys at a time).
__global__ __launch_bounds__(128)
void attn_kernel(const bf16* __restrict__ Qr, const bf16* __restrict__ Kr,
                 const bf16* __restrict__ Vt, bf16* __restrict__ Ob) {
    __shared__ __align__(16) bf16 lK0[64 * 64], lK1[64 * 64];   // 8 KB each
    __shared__ __align__(16) bf16 lV0[64 * 64], lV1[64 * 64];   // 8 KB each
    __shared__ __align__(16) bf16 lP[2][32][34];                // 4.25 KB

    const int t = threadIdx.x;
    const int w = t >> 6, lane = t & 63;
    const int l32 = lane & 31, hi = lane >> 5;
    const int bh = blockIdx.y;
    const int b = bh >> 4, h = bh & 15;
    const int qblk = 31 - (int)blockIdx.x;    // longest blocks first
    const int q = qblk * 64 + w * 32 + l32;

    const bf16* Qb = Qr + (size_t)bh * S_ * 64;   // (S, 64) pre-scaled
    const bf16* Kb = Kr + (size_t)bh * S_ * 64;   // (S, 64)
    const bf16* Vb = Vt + (size_t)bh * 64 * S_;   // (64, S)

    const int srow = t >> 3;                 // 0..15
    const int sj   = (t & 7) ^ (srow & 7);   // swizzled chunk (rounds add multiples of 16 rows)

    // Q fragments (B-operand: n = q = lane&31, k = hi*8+j), 4 dk-slices of 16
    short8 bq[4];
    {
        const bf16* qrow = Qb + (size_t)q * 64;
#pragma unroll
        for (int ks = 0; ks < 4; ks++)
            bq[ks] = *(const short8*)(qrow + ks * 16 + hi * 8);
    }

    float lacc = 0.f;
    floatx16 o[2];
#pragma unroll
    for (int dt = 0; dt < 2; dt++)
#pragma unroll
        for (int r = 0; r < 16; r++) o[dt][r] = 0.f;

    auto stage = [&](bf16* dK, bf16* dV, int kb) {
#pragma unroll
        for (int r = 0; r < 4; r++)
            load_lds16(Kb + (size_t)(kb + r * 16 + srow) * 64 + sj * 8,
                       dK + r * 1024 + t * 8);
#pragma unroll
        for (int r = 0; r < 4; r++)
            load_lds16(Vb + (size_t)(r * 16 + srow) * S_ + kb + sj * 8,
                       dV + r * 1024 + t * 8);
    };

    auto computeStep = [&](const bf16* lKc, const bf16* lVc, int kb, bool need_mask) {
#pragma unroll
        for (int kt = 0; kt < 2; kt++) {        // two 32-key tiles
            floatx16 z;
#pragma unroll
            for (int r = 0; r < 16; r++) z[r] = 0.f;
            const int krow = kt * 32 + l32;
#pragma unroll
            for (int ks = 0; ks < 4; ks++) {    // dk slices
                const short8 ak = *(const short8*)
                    &lKc[krow * 64 + (((ks * 2 + hi) ^ (krow & 7)) * 8)];
                z = __builtin_amdgcn_mfma_f32_32x32x16_bf16(ak, bq[ks], z, 0, 0, 0);
            }
            // exp + sum + pack P into LDS (C-layout: key_local=(r&3)+8*(r>>2)+4*hi)
            float p[16];
#pragma unroll
            for (int r = 0; r < 16; r++) {
                float v = z[r];
                if (need_mask) {
                    const int key = kb + kt * 32 + (r & 3) + 8 * (r >> 2) + 4 * hi;
                    if (key > q) v = -1e30f;
                }
                p[r] = __builtin_amdgcn_exp2f(v);
                lacc += p[r];
            }
#pragma unroll
            for (int rq = 0; rq < 4; rq++)
                *(uint2*)&lP[w][l32][8 * rq + 4 * hi] =
                    make_uint2(pack2bf16(p[rq * 4 + 0], p[rq * 4 + 1]),
                               pack2bf16(p[rq * 4 + 2], p[rq * 4 + 3]));
            // PV for this 32-key tile: 2 key-slices x 2 d-tiles
#pragma unroll
            for (int kl = 0; kl < 2; kl++) {
                const short8 bp = *(const short8*)&lP[w][l32][kl * 16 + hi * 8];
#pragma unroll
                for (int dt = 0; dt < 2; dt++) {
                    const int vrow = dt * 32 + l32;
                    const short8 av = *(const short8*)
                        &lVc[vrow * 64 + (((kt * 4 + kl * 2 + hi) ^ (vrow & 7)) * 8)];
                    o[dt] = __builtin_amdgcn_mfma_f32_32x32x16_bf16(av, bp, o[dt], 0, 0, 0);
                }
            }
        }
    };

    const int nsteps = qblk + 1;
    stage(lK0, lV0, 0);
    __syncthreads();
    for (int st = 0; st < nsteps; ++st) {
        const bool even = (st & 1) == 0;
        const bf16* cK = even ? lK0 : lK1;  const bf16* cV = even ? lV0 : lV1;
        bf16* nK = even ? lK1 : lK0;        bf16* nV = even ? lV1 : lV0;
        if (st + 1 < nsteps) stage(nK, nV, (st + 1) * 64);
        computeStep(cK, cV, st * 64, st == nsteps - 1);
        __syncthreads();
    }

    // epilogue: l reduce (keys split across hi only) + normalized store
    float l = lacc + __shfl_xor(lacc, 32);
    const float invl = 1.0f / l;
    bf16* orow = Ob + ((size_t)(b * S_ + q) * H_ + h) * 64;
#pragma unroll
    for (int dt = 0; dt < 2; dt++)
#pragma unroll
        for (int rq = 0; rq < 4; rq++) {
            const int d = dt * 32 + 8 * rq + 4 * hi;
            *(uint2*)(orow + d) =
                make_uint2(pack2bf16(o[dt][rq * 4 + 0] * invl, o[dt][rq * 4 + 1] * invl),
                           pack2bf16(o[dt][rq * 4 + 2] * invl, o[dt][rq * 4 + 3] * invl));
        }
}

// ---------------- out GEMM (BK=64, swizzled): C[M,1024] = A * Wo^T, 128x64 tile ----------------
__global__ __launch_bounds__(256)
void gemm_out(const bf16* __restrict__ A, const bf16* __restrict__ Bw,
              float* __restrict__ C) {
    __shared__ __align__(16) bf16 lA[128 * 64];   // 16 KB
    __shared__ __align__(16) bf16 lB[64 * 64];    //  8 KB
    const int t = threadIdx.x;
    const int lane = t & 63, w = t >> 6;
    const int quad = lane >> 4, l16 = lane & 15;
    const int m0 = blockIdx.x * 128, n0 = blockIdx.y * 64;
    const int wm = (w & 1) * 64, wn = (w >> 1) * 32;

    floatx4 acc[4][2];
#pragma unroll
    for (int i = 0; i < 4; i++)
#pragma unroll
        for (int j = 0; j < 2; j++) acc[i][j] = (floatx4){0.f, 0.f, 0.f, 0.f};

    const int srow = t >> 3;
    const int sj   = (t & 7) ^ (srow & 7);

    for (int kt = 0; kt < D_; kt += 64) {
#pragma unroll
        for (int r = 0; r < 4; r++)
            load_lds16(A + (size_t)(m0 + r * 32 + srow) * D_ + kt + sj * 8,
                       lA + r * 2048 + t * 8);
#pragma unroll
        for (int r = 0; r < 2; r++)
            load_lds16(Bw + (size_t)(n0 + r * 32 + srow) * D_ + kt + sj * 8,
                       lB + r * 2048 + t * 8);
        __syncthreads();

#pragma unroll
        for (int kh = 0; kh < 2; kh++) {
            short8 af[4], bfr[2];
#pragma unroll
            for (int i = 0; i < 4; i++) {
                const int row = wm + i * 16 + l16;
                af[i] = *(const short8*)&lA[row * 64 + ((kh * 4 + quad) ^ (row & 7)) * 8];
            }
#pragma unroll
            for (int j = 0; j < 2; j++) {
                const int row = wn + j * 16 + l16;
                bfr[j] = *(const short8*)&lB[row * 64 + ((kh * 4 + quad) ^ (row & 7)) * 8];
            }
#pragma unroll
            for (int i = 0; i < 4; i++)
#pragma unroll
                for (int j = 0; j < 2; j++)
                    acc[i][j] = __builtin_amdgcn_mfma_f32_16x16x32_bf16(af[i], bfr[j], acc[i][j], 0, 0, 0);
        }
        __syncthreads();
    }

#pragma unroll
    for (int i = 0; i < 4; i++) {
        const int row = m0 + wm + i * 16 + quad * 4;
#pragma unroll
        for (int j = 0; j < 2; j++) {
            const int col = n0 + wn + j * 16 + l16;
#pragma unroll
            for (int r = 0; r < 4; r++)
                C[(size_t)(row + r) * D_ + col] = acc[i][j][r];
        }
    }
}

// ---------------- launch ----------------
extern "C" void kernel_launch(void* const* d_in, const int* in_sizes, int n_in,
                              void* d_out, int out_size, void* d_ws, size_t ws_size,
                              hipStream_t stream) {
    const float* x  = (const float*)d_in[0];
    const float* Wq = (const float*)d_in[1];
    const float* Wk = (const float*)d_in[2];
    const float* Wv = (const float*)d_in[3];
    const float* Wo = (const float*)d_in[4];
    float* out = (float*)d_out;

    char* ws = (char*)d_ws;
    bf16* xb   = (bf16*)(ws);                    //  [0,8) MiB
    bf16* Wcat = (bf16*)(ws + 8388608);          //  [8,14)
    bf16* Wob  = (bf16*)(ws + 14680064);         //  [14,16)
    bf16* QKVb = (bf16*)(ws + 16777216);         //  [16,40)  Q,K cols (stride 3072)
    bf16* Qr   = (bf16*)(ws + 41943040);         //  [40,48)  (B,H,S,64) rope'd, scaled
    bf16* Kr   = (bf16*)(ws + 50331648);         //  [48,56)  (B,H,S,64) rope'd
    bf16* Vt   = (bf16*)(ws + 58720256);         //  [56,64)  (B,H,64,S)
    bf16* Ob   = QKVb;                           //  alias: QKVb dead after rope

    cvt_all<<<8192, 256, 0, stream>>>(x, Wq, Wk, Wv, Wo, xb, Wcat, Wob);
    gemm_qkv<<<dim3(32, 24), 256, 0, stream>>>(xb, Wcat, QKVb, Vt);
    rope_kernel<<<8192, 256, 0, stream>>>(QKVb, Qr, Kr);
    attn_kernel<<<dim3(32, B_ * H_), 128, 0, stream>>>(Qr, Kr, Vt, Ob);
    gemm_out<<<dim3(32, 16), 256, 0, stream>>>(Ob, Wob, out);
}

// Round 9
// 197.088 us; speedup vs baseline: 1.0599x; 1.0599x over previous
//
#include <hip/hip_runtime.h>
#include <hip/hip_bf16.h>

// Problem constants (B=2, S=2048, D=1024, H=16, dk=64)
#define B_   2
#define S_   2048
#define H_   16
#define DK_  64
#define D_   1024
#define BS_  4096   // B*S
#define N3_  3072   // 3*D

typedef __attribute__((ext_vector_type(8))) short short8;    // 8 x bf16 (4 VGPRs)
typedef __attribute__((ext_vector_type(4))) float floatx4;   // 16x16 MFMA acc
typedef __hip_bfloat16 bf16;

__device__ inline void load_lds16(const bf16* g, bf16* l) {
    __builtin_amdgcn_global_load_lds(
        (const __attribute__((address_space(1))) void*)g,
        (__attribute__((address_space(3))) void*)l, 16, 0, 0);
}

__device__ inline unsigned int pack2bf16(float a, float b) {
    __hip_bfloat162 h = __float22bfloat162_rn(make_float2(a, b));
    return *(unsigned int*)&h;
}

// ---------------- fused fp32 -> bf16 convert for all inputs (1 launch) ----------------
__global__ void cvt_all(const float* __restrict__ x,  const float* __restrict__ wq,
                        const float* __restrict__ wk, const float* __restrict__ wv,
                        const float* __restrict__ wo,
                        bf16* __restrict__ xb, bf16* __restrict__ wcat, bf16* __restrict__ wob) {
    const int blk = blockIdx.x;
    const float* src; bf16* dst; int base;
    if (blk < 4096)      { src = x;  dst = xb;             base = blk * 1024; }
    else if (blk < 5120) { src = wq; dst = wcat;           base = (blk - 4096) * 1024; }
    else if (blk < 6144) { src = wk; dst = wcat + 1048576; base = (blk - 5120) * 1024; }
    else if (blk < 7168) { src = wv; dst = wcat + 2097152; base = (blk - 6144) * 1024; }
    else                 { src = wo; dst = wob;            base = (blk - 7168) * 1024; }
    const int i = base + threadIdx.x * 4;
    float4 v = *(const float4*)(src + i);
    *(uint2*)(dst + i) = make_uint2(pack2bf16(v.x, v.y), pack2bf16(v.z, v.w));
}

// ---------------- QKV GEMM (BK=64, swizzled LDS): Q,K -> QKVb rows; V -> Vt ----------------
__global__ __launch_bounds__(256)
void gemm_qkv(const bf16* __restrict__ A, const bf16* __restrict__ Bw,
              bf16* __restrict__ Cqk, bf16* __restrict__ Vt) {
    __shared__ __align__(16) bf16 lA[128 * 64];   // 16 KB
    __shared__ __align__(16) bf16 lB[128 * 64];   // 16 KB
    const int t = threadIdx.x;
    const int lane = t & 63, w = t >> 6;
    const int quad = lane >> 4, l16 = lane & 15;
    const int m0 = blockIdx.x * 128, n0 = blockIdx.y * 128;
    const int wm = (w & 1) * 64, wn = (w >> 1) * 64;

    floatx4 acc[4][4];
#pragma unroll
    for (int i = 0; i < 4; i++)
#pragma unroll
        for (int j = 0; j < 4; j++) acc[i][j] = (floatx4){0.f, 0.f, 0.f, 0.f};

    const int srow = t >> 3;                 // 0..31
    const int sj   = (t & 7) ^ (srow & 7);   // XOR-swizzled 16B chunk

    for (int kt = 0; kt < D_; kt += 64) {
#pragma unroll
        for (int r = 0; r < 4; r++)
            load_lds16(A + (size_t)(m0 + r * 32 + srow) * D_ + kt + sj * 8,
                       lA + r * 2048 + t * 8);
#pragma unroll
        for (int r = 0; r < 4; r++)
            load_lds16(Bw + (size_t)(n0 + r * 32 + srow) * D_ + kt + sj * 8,
                       lB + r * 2048 + t * 8);
        __syncthreads();

#pragma unroll
        for (int kh = 0; kh < 2; kh++) {
            short8 af[4], bfr[4];
#pragma unroll
            for (int i = 0; i < 4; i++) {
                const int row = wm + i * 16 + l16;
                af[i] = *(const short8*)&lA[row * 64 + ((kh * 4 + quad) ^ (row & 7)) * 8];
            }
#pragma unroll
            for (int j = 0; j < 4; j++) {
                const int row = wn + j * 16 + l16;
                bfr[j] = *(const short8*)&lB[row * 64 + ((kh * 4 + quad) ^ (row & 7)) * 8];
            }
#pragma unroll
            for (int i = 0; i < 4; i++)
#pragma unroll
                for (int j = 0; j < 4; j++)
                    acc[i][j] = __builtin_amdgcn_mfma_f32_16x16x32_bf16(af[i], bfr[j], acc[i][j], 0, 0, 0);
        }
        __syncthreads();
    }

    if (n0 < 2 * D_) {
        // Q,K columns: row-major coalesced store
#pragma unroll
        for (int i = 0; i < 4; i++) {
            const int row = m0 + wm + i * 16 + quad * 4;
#pragma unroll
            for (int j = 0; j < 4; j++) {
                const int col = n0 + wn + j * 16 + l16;
#pragma unroll
                for (int r = 0; r < 4; r++)
                    Cqk[(size_t)(row + r) * N3_ + col] = __float2bfloat16(acc[i][j][r]);
            }
        }
    } else {
        // V columns: transposed packed store into Vt (B,H,64,S)
#pragma unroll
        for (int i = 0; i < 4; i++) {
            const int row0 = m0 + wm + i * 16 + quad * 4;
            const int bb = row0 >> 11;
            const int ss = row0 & 2047;
#pragma unroll
            for (int j = 0; j < 4; j++) {
                const int c = n0 + wn + j * 16 + l16 - 2 * D_;
                const int h = c >> 6, d = c & 63;
                *(uint2*)(Vt + (((size_t)bb * H_ + h) * 64 + d) * S_ + ss) =
                    make_uint2(pack2bf16(acc[i][j][0], acc[i][j][1]),
                               pack2bf16(acc[i][j][2], acc[i][j][3]));
            }
        }
    }
}

// ---------------- RoPE: QKV (B,S,3D) -> Qr (scaled by log2e/sqrt(dk)), Kr (B,H,S,64) ----------------
__global__ void rope_kernel(const bf16* __restrict__ QKV,
                            bf16* __restrict__ Qr, bf16* __restrict__ Kr) {
    int tid = blockIdx.x * blockDim.x + threadIdx.x;
    if (tid >= B_ * S_ * H_ * 32) return;
    const int i = tid & 31;
    const int h = (tid >> 5) & (H_ - 1);
    const int bs = tid >> 9;
    const int s = bs & (S_ - 1);
    const int b = bs >> 11;

    const bf16* base = QKV + (size_t)bs * N3_ + h * 64 + 2 * i;
    const float q0 = __bfloat162float(base[0]);
    const float q1 = __bfloat162float(base[1]);
    const float k0 = __bfloat162float(base[D_]);
    const float k1 = __bfloat162float(base[D_ + 1]);

    const float freq = exp2f(-(float)(2 * i) * 0.2076205059304601f);  // theta^(-2i/64)
    const float ang = (float)s * freq;
    float sn, cs;
    sincosf(ang, &sn, &cs);

    const float QS = 0.18033688011112042f;   // log2(e)/sqrt(64)
    const size_t off = ((size_t)(b * H_ + h) * S_ + s) * 64 + 2 * i;
    *(unsigned int*)(Qr + off) = pack2bf16((q0 * cs - q1 * sn) * QS, (q0 * sn + q1 * cs) * QS);
    *(unsigned int*)(Kr + off) = pack2bf16(k0 * cs - k1 * sn, k0 * sn + k1 * cs);
}

// ---------------- Flash attention (causal), q-tile 128, 512 threads, 16x16 MFMA ----------------
// grid (16, 32): qblk = 15 - blockIdx.x (longest first), 8 waves x 16 q-rows.
// LDS 41 KB -> 3 blocks/CU = 24 waves/CU. One staged 64-key step feeds 8 waves
// (2x compute per barrier vs the 64-q version). Chunked conflict-free P.
// Fixed-max base-2 softmax (Q pre-scaled by log2e/sqrt(dk)); per-wave causal
// step skip + mask only on each wave's boundary step.
__global__ __launch_bounds__(512)
void attn_kernel(const bf16* __restrict__ Qr, const bf16* __restrict__ Kr,
                 const bf16* __restrict__ Vt, bf16* __restrict__ Ob) {
    __shared__ __align__(16) bf16 lK0[64 * 64], lK1[64 * 64];   // 8 KB each
    __shared__ __align__(16) bf16 lV0[64 * 64], lV1[64 * 64];   // 8 KB each
    __shared__ __align__(16) bf16 lP[8][16][36];                // 9 KB

    const int t = threadIdx.x;
    const int w = t >> 6, lane = t & 63;
    const int quad = lane >> 4, l16 = lane & 15;
    const int bh = blockIdx.y;
    const int b = bh >> 4, h = bh & 15;
    const int qblk = 15 - (int)blockIdx.x;    // longest blocks first
    const int q0w = qblk * 128 + w * 16;
    const int q = q0w + l16;

    const bf16* Qb = Qr + (size_t)bh * S_ * 64;   // (S, 64) pre-scaled
    const bf16* Kb = Kr + (size_t)bh * S_ * 64;   // (S, 64)
    const bf16* Vb = Vt + (size_t)bh * 64 * S_;   // (64, S)

    // staging: 512 threads x 16B = one full 64x64 bf16 tile per call
    const int srow = t >> 3;                 // 0..63
    const int sj   = (t & 7) ^ (srow & 7);   // XOR-swizzled 16B chunk
    const int swz = l16 & 7;
    const int pA = quad ^ swz;
    const int pB = (4 + quad) ^ swz;

    // Q fragment (B-operand: n = l16 = q row, k = quad*8+j)
    const bf16* qrow = Qb + (size_t)q * 64;
    short8 bq[2];
    bq[0] = *(const short8*)(qrow + quad * 8);
    bq[1] = *(const short8*)(qrow + 32 + quad * 8);

    float lacc = 0.f;
    floatx4 o[4];
#pragma unroll
    for (int ct = 0; ct < 4; ct++) o[ct] = (floatx4){0.f, 0.f, 0.f, 0.f};

    auto stage = [&](bf16* dK, bf16* dV, int kb) {
        load_lds16(Kb + (size_t)(kb + srow) * 64 + sj * 8, dK + t * 8);
        load_lds16(Vb + (size_t)srow * S_ + kb + sj * 8,   dV + t * 8);
    };

    auto computeStep = [&](const bf16* lKc, const bf16* lVc, int kb, bool need_mask) {
#pragma unroll
        for (int c = 0; c < 2; c++) {
            floatx4 s[2];
#pragma unroll
            for (int k2 = 0; k2 < 2; k2++) {
                const int kt = c * 2 + k2;
                const short8 k0 = *(const short8*)&lKc[(kt * 16 + l16) * 64 + pA * 8];
                const short8 k1 = *(const short8*)&lKc[(kt * 16 + l16) * 64 + pB * 8];
                floatx4 z = (floatx4){0.f, 0.f, 0.f, 0.f};
                z = __builtin_amdgcn_mfma_f32_16x16x32_bf16(k0, bq[0], z, 0, 0, 0);
                z = __builtin_amdgcn_mfma_f32_16x16x32_bf16(k1, bq[1], z, 0, 0, 0);
                s[k2] = z;
            }
            float rs = 0.f;
#pragma unroll
            for (int k2 = 0; k2 < 2; k2++) {
                float p[4];
#pragma unroll
                for (int r = 0; r < 4; r++) {
                    float v = s[k2][r];
                    if (need_mask) {
                        const int key = kb + (c * 2 + k2) * 16 + quad * 4 + r;
                        if (key > q) v = -1e30f;
                    }
                    p[r] = __builtin_amdgcn_exp2f(v);
                    rs += p[r];
                }
                *(uint2*)&lP[w][l16][k2 * 16 + quad * 4] =
                    make_uint2(pack2bf16(p[0], p[1]), pack2bf16(p[2], p[3]));
            }
            lacc += rs;
            const int pc = c ? pB : pA;
            const short8 bp = *(const short8*)&lP[w][l16][quad * 8];
#pragma unroll
            for (int ct = 0; ct < 4; ct++) {
                const short8 av = *(const short8*)&lVc[(ct * 16 + l16) * 64 + pc * 8];
                o[ct] = __builtin_amdgcn_mfma_f32_16x16x32_bf16(av, bp, o[ct], 0, 0, 0);
            }
        }
    };

    const int nsteps = 2 * qblk + 2;          // block-level steps
    const int nst_w  = (q0w + 79) >> 6;       // steps THIS wave needs (causal)
    stage(lK0, lV0, 0);
    __syncthreads();
    for (int st = 0; st < nsteps; ++st) {
        const bool even = (st & 1) == 0;
        const bf16* cK = even ? lK0 : lK1;  const bf16* cV = even ? lV0 : lV1;
        bf16* nK = even ? lK1 : lK0;        bf16* nV = even ? lV1 : lV0;
        if (st + 1 < nsteps) stage(nK, nV, (st + 1) * 64);
        if (st < nst_w) computeStep(cK, cV, st * 64, st == nst_w - 1);
        __syncthreads();
    }

    // epilogue: l reduce + normalized store
    float l = lacc;
    l += __shfl_xor(l, 16);
    l += __shfl_xor(l, 32);
    const float invl = 1.0f / l;
    bf16* orow = Ob + ((size_t)(b * S_ + q) * H_ + h) * 64;
#pragma unroll
    for (int ct = 0; ct < 4; ct++)
        *(uint2*)(orow + ct * 16 + quad * 4) =
            make_uint2(pack2bf16(o[ct][0] * invl, o[ct][1] * invl),
                       pack2bf16(o[ct][2] * invl, o[ct][3] * invl));
}

// ---------------- out GEMM (BK=64, swizzled): C[M,1024] = A * Wo^T, 128x64 tile ----------------
__global__ __launch_bounds__(256)
void gemm_out(const bf16* __restrict__ A, const bf16* __restrict__ Bw,
              float* __restrict__ C) {
    __shared__ __align__(16) bf16 lA[128 * 64];   // 16 KB
    __shared__ __align__(16) bf16 lB[64 * 64];    //  8 KB
    const int t = threadIdx.x;
    const int lane = t & 63, w = t >> 6;
    const int quad = lane >> 4, l16 = lane & 15;
    const int m0 = blockIdx.x * 128, n0 = blockIdx.y * 64;
    const int wm = (w & 1) * 64, wn = (w >> 1) * 32;

    floatx4 acc[4][2];
#pragma unroll
    for (int i = 0; i < 4; i++)
#pragma unroll
        for (int j = 0; j < 2; j++) acc[i][j] = (floatx4){0.f, 0.f, 0.f, 0.f};

    const int srow = t >> 3;
    const int sj   = (t & 7) ^ (srow & 7);

    for (int kt = 0; kt < D_; kt += 64) {
#pragma unroll
        for (int r = 0; r < 4; r++)
            load_lds16(A + (size_t)(m0 + r * 32 + srow) * D_ + kt + sj * 8,
                       lA + r * 2048 + t * 8);
#pragma unroll
        for (int r = 0; r < 2; r++)
            load_lds16(Bw + (size_t)(n0 + r * 32 + srow) * D_ + kt + sj * 8,
                       lB + r * 2048 + t * 8);
        __syncthreads();

#pragma unroll
        for (int kh = 0; kh < 2; kh++) {
            short8 af[4], bfr[2];
#pragma unroll
            for (int i = 0; i < 4; i++) {
                const int row = wm + i * 16 + l16;
                af[i] = *(const short8*)&lA[row * 64 + ((kh * 4 + quad) ^ (row & 7)) * 8];
            }
#pragma unroll
            for (int j = 0; j < 2; j++) {
                const int row = wn + j * 16 + l16;
                bfr[j] = *(const short8*)&lB[row * 64 + ((kh * 4 + quad) ^ (row & 7)) * 8];
            }
#pragma unroll
            for (int i = 0; i < 4; i++)
#pragma unroll
                for (int j = 0; j < 2; j++)
                    acc[i][j] = __builtin_amdgcn_mfma_f32_16x16x32_bf16(af[i], bfr[j], acc[i][j], 0, 0, 0);
        }
        __syncthreads();
    }

#pragma unroll
    for (int i = 0; i < 4; i++) {
        const int row = m0 + wm + i * 16 + quad * 4;
#pragma unroll
        for (int j = 0; j < 2; j++) {
            const int col = n0 + wn + j * 16 + l16;
#pragma unroll
            for (int r = 0; r < 4; r++)
                C[(size_t)(row + r) * D_ + col] = acc[i][j][r];
        }
    }
}

// ---------------- launch ----------------
extern "C" void kernel_launch(void* const* d_in, const int* in_sizes, int n_in,
                              void* d_out, int out_size, void* d_ws, size_t ws_size,
                              hipStream_t stream) {
    const float* x  = (const float*)d_in[0];
    const float* Wq = (const float*)d_in[1];
    const float* Wk = (const float*)d_in[2];
    const float* Wv = (const float*)d_in[3];
    const float* Wo = (const float*)d_in[4];
    float* out = (float*)d_out;

    char* ws = (char*)d_ws;
    bf16* xb   = (bf16*)(ws);                    //  [0,8) MiB
    bf16* Wcat = (bf16*)(ws + 8388608);          //  [8,14)
    bf16* Wob  = (bf16*)(ws + 14680064);         //  [14,16)
    bf16* QKVb = (bf16*)(ws + 16777216);         //  [16,40)  Q,K cols (stride 3072)
    bf16* Qr   = (bf16*)(ws + 41943040);         //  [40,48)  (B,H,S,64) rope'd, scaled
    bf16* Kr   = (bf16*)(ws + 50331648);         //  [48,56)  (B,H,S,64) rope'd
    bf16* Vt   = (bf16*)(ws + 58720256);         //  [56,64)  (B,H,64,S)
    bf16* Ob   = QKVb;                           //  alias: QKVb dead after rope

    cvt_all<<<8192, 256, 0, stream>>>(x, Wq, Wk, Wv, Wo, xb, Wcat, Wob);
    gemm_qkv<<<dim3(32, 24), 256, 0, stream>>>(xb, Wcat, QKVb, Vt);
    rope_kernel<<<8192, 256, 0, stream>>>(QKVb, Qr, Kr);
    attn_kernel<<<dim3(16, B_ * H_), 512, 0, stream>>>(Qr, Kr, Vt, Ob);
    gemm_out<<<dim3(32, 16), 256, 0, stream>>>(Ob, Wob, out);
}